// Round 5
// baseline (671.029 us; speedup 1.0000x reference)
//
#include <hip/hip_runtime.h>
#include <hip/hip_bf16.h>
#include <math.h>

#define B_ 4
#define S_ 1024
#define D_ 1024
#define H_ 16
#define DK_ 64

typedef short bf16x8 __attribute__((ext_vector_type(8)));
typedef float f32x4 __attribute__((ext_vector_type(4)));

#define MFMA(a, b, c) __builtin_amdgcn_mfma_f32_16x16x32_bf16(a, b, c, 0, 0, 0)

// async global->LDS, 16B per lane. Effective LDS dest = wave-uniform base + lane*16.
#define GLDS(gp, lp)                                                        \
    __builtin_amdgcn_global_load_lds(                                       \
        (const __attribute__((address_space(1))) void*)(const void*)(gp),   \
        (__attribute__((address_space(3))) void*)(void*)(lp), 16, 0, 0)

static __device__ __forceinline__ unsigned short f2bf(float f) {
    __hip_bfloat16 h = __float2bfloat16(f);
    return *reinterpret_cast<unsigned short*>(&h);
}

// ---------------------------------------------------------------------------
// fused f32->bf16 converts: 3 activations (12288 blocks) + 4 weights (4096)
// ---------------------------------------------------------------------------
__global__ __launch_bounds__(256) void cvt_all(
    const float* __restrict__ a, const float* __restrict__ b, const float* __restrict__ c,
    const float* __restrict__ wa, const float* __restrict__ wb,
    const float* __restrict__ wc, const float* __restrict__ wd,
    unsigned short* __restrict__ oa, unsigned short* __restrict__ ob, unsigned short* __restrict__ oc,
    unsigned short* __restrict__ owa, unsigned short* __restrict__ owb,
    unsigned short* __restrict__ owc, unsigned short* __restrict__ owd)
{
    int bx = blockIdx.x;
    const float* in; unsigned short* out; int i;
    if (bx < 12288) {
        int which = bx >> 12;
        in  = which == 0 ? a : which == 1 ? b : c;
        out = which == 0 ? oa : which == 1 ? ob : oc;
        i = (bx & 4095) * 256 + threadIdx.x;
    } else {
        int b2 = bx - 12288;
        int which = b2 >> 10;
        in  = which == 0 ? wa : which == 1 ? wb : which == 2 ? wc : wd;
        out = which == 0 ? owa : which == 1 ? owb : which == 2 ? owc : owd;
        i = (b2 & 1023) * 256 + threadIdx.x;
    }
    float4 v = ((const float4*)in)[i];
    ushort4 o;
    o.x = f2bf(v.x); o.y = f2bf(v.y); o.z = f2bf(v.z); o.w = f2bf(v.w);
    ((ushort4*)out)[i] = o;
}

// ---------------------------------------------------------------------------
// m97-shape bf16 MFMA GEMM for QKV projections: C[4096,1024] = X @ W^T + bvec.
// Tile 128x128, BK=32, 4 waves of 64x64. blockIdx.z selects (X,W,b,Y).
// z=0: Q-proj -> bf16, *0.125, zero masked rows
// z=1: K-proj -> bf16 row-major
// z=2: V-proj -> bf16 transposed [(b*1024+n)][s]
// ---------------------------------------------------------------------------
__global__ __launch_bounds__(256, 2) void gemm128(
    const unsigned short* __restrict__ X0, const unsigned short* __restrict__ X1,
    const unsigned short* __restrict__ X2,
    const unsigned short* __restrict__ W0, const unsigned short* __restrict__ W1,
    const unsigned short* __restrict__ W2,
    const float* __restrict__ bv0, const float* __restrict__ bv1,
    const float* __restrict__ bv2,
    unsigned short* __restrict__ Y0, unsigned short* __restrict__ Y1,
    unsigned short* __restrict__ Y2,
    const int* __restrict__ mask)
{
    __shared__ unsigned short As[128 * 32];
    __shared__ unsigned short Bs[128 * 32];

    const int z = blockIdx.z;
    const unsigned short* X = z == 0 ? X0 : z == 1 ? X1 : X2;
    const unsigned short* W = z == 0 ? W0 : z == 1 ? W1 : W2;
    const float* bvec = z == 0 ? bv0 : z == 1 ? bv1 : bv2;
    unsigned short* Y = z == 0 ? Y0 : z == 1 ? Y1 : Y2;

    const int t = threadIdx.x;
    const int w = t >> 6, l = t & 63;
    const int lane16 = l & 15, quad = l >> 4;
    const int m0 = blockIdx.y * 128, n0 = blockIdx.x * 128;
    const int wr = w >> 1, wc = w & 1;

    const int srow = w * 16 + (l >> 2);
    const unsigned short* agp = X + (size_t)(m0 + srow) * 1024 + (l & 3) * 8;
    const unsigned short* bgp = W + (size_t)(n0 + srow) * 1024 + (l & 3) * 8;
    unsigned short* alp = As + w * 512 + l * 8;
    unsigned short* blp = Bs + w * 512 + l * 8;

    f32x4 zero = {0.f, 0.f, 0.f, 0.f};
    f32x4 acc[4][4];
    #pragma unroll
    for (int i = 0; i < 4; ++i)
        #pragma unroll
        for (int j = 0; j < 4; ++j) acc[i][j] = zero;

    for (int kt = 0; kt < 1024; kt += 32) {
        GLDS(agp + kt, alp);
        GLDS(agp + kt + 64 * 1024, alp + 2048);
        GLDS(bgp + kt, blp);
        GLDS(bgp + kt + 64 * 1024, blp + 2048);
        __syncthreads();

        bf16x8 af[4], bfv[4];
        #pragma unroll
        for (int i = 0; i < 4; ++i)
            af[i] = *(const bf16x8*)(As + (wr * 64 + i * 16 + lane16) * 32 + quad * 8);
        #pragma unroll
        for (int j = 0; j < 4; ++j)
            bfv[j] = *(const bf16x8*)(Bs + (wc * 64 + j * 16 + lane16) * 32 + quad * 8);

        #pragma unroll
        for (int i = 0; i < 4; ++i)
            #pragma unroll
            for (int j = 0; j < 4; ++j)
                acc[i][j] = MFMA(af[i], bfv[j], acc[i][j]);
        __syncthreads();
    }

    float bvl[4];
    #pragma unroll
    for (int j = 0; j < 4; ++j) bvl[j] = bvec[n0 + wc * 64 + j * 16 + lane16];

    if (z == 2) {
        // V transposed: out[(b*1024+n)][s], pack 4 consecutive s
        const int bb = m0 >> 10;
        const int sb = (m0 & 1023) + wr * 64;
        #pragma unroll
        for (int i = 0; i < 4; ++i) {
            #pragma unroll
            for (int j = 0; j < 4; ++j) {
                int n = n0 + wc * 64 + j * 16 + lane16;
                ushort4 pk;
                pk.x = f2bf(acc[i][j][0] + bvl[j]);
                pk.y = f2bf(acc[i][j][1] + bvl[j]);
                pk.z = f2bf(acc[i][j][2] + bvl[j]);
                pk.w = f2bf(acc[i][j][3] + bvl[j]);
                int s = sb + i * 16 + quad * 4;
                *(ushort4*)(Y + ((size_t)(bb * 1024 + n)) * 1024 + s) = pk;
            }
        }
    } else {
        #pragma unroll
        for (int i = 0; i < 4; ++i) {
            int mrow[4];
            #pragma unroll
            for (int r = 0; r < 4; ++r)
                mrow[r] = (z == 0) ? mask[m0 + wr * 64 + i * 16 + quad * 4 + r] : 1;
            #pragma unroll
            for (int j = 0; j < 4; ++j) {
                int n = n0 + wc * 64 + j * 16 + lane16;
                #pragma unroll
                for (int r = 0; r < 4; ++r) {
                    size_t m = m0 + wr * 64 + i * 16 + quad * 4 + r;
                    float val = acc[i][j][r] + bvl[j];
                    if (z == 0) val = mrow[r] ? val * 0.125f : 0.f;
                    Y[m * 1024 + n] = f2bf(val);
                }
            }
        }
    }
}

// ---------------------------------------------------------------------------
// MFMA flash attention, double-buffered K/V, ONE barrier per k-tile.
// Block = (b,h,64 q), 4 waves x 16 q rows. LDS = 40 KB -> 4 blocks/CU.
// This round: prep_bias is GONE. Attn streams the RAW f32 bias tensor:
//  - 16 scalar f32 loads per lane per k-tile, issued BEFORE the next-tile
//    GLDS so the bias wait is vmcnt(4), not a prefetch-draining vmcnt(0).
//  - mask + /8 folded in-register: s = mq ? fma(bias,0.125, qk + mkadd) : NEG
//    (masked-q rows become exactly-uniform NEG rows, matching reference).
//  - block remap bid = h*64 + b*16 + qt: the 16 heads sharing each 64B bias
//    line (h is innermost, 16h x 4B = 1 line) land on the SAME XCD
//    (bid%8 = qt%8) -> L2 absorbs the 16x line amplification; HBM reads
//    bias ~once (256 MB) vs prep's 256R+128W + attn's 128R = 512 MB.
//    K/V (16 MB total) sacrificed from XCD-locality is L3-served.
// ---------------------------------------------------------------------------
__global__ __launch_bounds__(256, 2) void attn_mfma(
    const unsigned short* __restrict__ Qp, const unsigned short* __restrict__ Kp,
    const unsigned short* __restrict__ VpT, const float* __restrict__ bias,
    const int* __restrict__ mask, unsigned short* __restrict__ Xp)
{
    __shared__ unsigned short Ks[2][64 * 64];
    __shared__ unsigned short Vs[2][64 * 64];
    __shared__ unsigned short Ps[4][16 * 64];

    const int t = threadIdx.x;
    const int w = t >> 6, l = t & 63;
    const int lane16 = l & 15, quad = l >> 4;

    const int bid = blockIdx.x;
    const int h = bid >> 6;             // heads grouped per XCD class
    const int b = (bid >> 4) & 3;
    const int qt = bid & 15;            // bid%8 = qt%8 -> (b,qt) group shares XCD
    const int qrow0 = qt * 64 + w * 16;

    const float NEGF = -28672.f;

    // Q fragments (bf16, pre-scaled by 0.125; masked rows zeroed)
    bf16x8 qf[2];
    #pragma unroll
    for (int c = 0; c < 2; ++c)
        qf[c] = *(const bf16x8*)(Qp + (size_t)(b * 1024 + qrow0 + lane16) * 1024
                                 + h * 64 + c * 32 + quad * 8);

    // all-ones bf16 fragment for row-sum MFMA
    bf16x8 ones;
    #pragma unroll
    for (int e = 0; e < 8; ++e) ones[e] = (short)0x3F80;

    // q-row mask (loop-invariant; rows quad*4+r of this wave's 16)
    int mq[4];
    #pragma unroll
    for (int r = 0; r < 4; ++r) mq[r] = mask[b * 1024 + qrow0 + quad * 4 + r];

    // raw bias base for this lane: bias[b][qrow0+quad*4][lane16][h]
    // per-(r,j) offsets: r*16384 + j*256 floats; per-tile advance: 1024 floats
    const float* bt = bias + ((size_t)(b * 1024 + qrow0 + quad * 4) * 1024 + lane16) * 16 + h;

    // K/V staging (xor-swizzled 16B granules within 128B rows)
    const int krow = w * 8 + (l >> 3);
    const int kgran = (l & 7) ^ ((l >> 3) & 7);
    const unsigned short* kg = Kp + (size_t)(b * 1024 + krow) * 1024 + h * 64 + kgran * 8;
    const unsigned short* vg = VpT + ((size_t)(b * 16 + h) * 64 + krow) * 1024 + kgran * 8;
    unsigned short* kst = &Ks[0][w * 512 + l * 8];
    unsigned short* vst = &Vs[0][w * 512 + l * 8];

    // prologue: stage tile 0 into buffer 0
    GLDS(kg, kst);
    GLDS(kg + (size_t)32 * 1024, kst + 32 * 64);
    GLDS(vg, vst);
    GLDS(vg + (size_t)32 * 1024, vst + 32 * 64);

    f32x4 zero = {0.f, 0.f, 0.f, 0.f};
    f32x4 o[4];
    #pragma unroll
    for (int j = 0; j < 4; ++j) o[j] = zero;
    float m_i[4] = {-1e30f, -1e30f, -1e30f, -1e30f};
    float l_i[4] = {0.f, 0.f, 0.f, 0.f};

    char* psb = (char*)&Ps[w][0];

    for (int kt16 = 0; kt16 < 16; ++kt16) {
        const int cur = kt16 & 1;
        __syncthreads();    // publishes tile kt16 (drains in-flight prefetch)

        // current-tile mask-k + bias loads FIRST (so their wait is vmcnt(4),
        // leaving the next-tile GLDS below still in flight)
        int mk[4];
        #pragma unroll
        for (int j = 0; j < 4; ++j)
            mk[j] = mask[b * 1024 + kt16 * 64 + j * 16 + lane16];
        float bfv[4][4];
        #pragma unroll
        for (int j = 0; j < 4; ++j)
            #pragma unroll
            for (int r = 0; r < 4; ++r)
                bfv[j][r] = bt[(size_t)r * 16384 + j * 256];

        // prefetch tile kt16+1 into the other buffer (uniform branch)
        if (kt16 < 15) {
            const size_t kn = (size_t)(kt16 + 1) * 64;
            unsigned short* kd = kst + (cur ^ 1) * 4096;
            unsigned short* vd = vst + (cur ^ 1) * 4096;
            GLDS(kg + kn * 1024, kd);
            GLDS(kg + (kn + 32) * 1024, kd + 32 * 64);
            GLDS(vg + kn, vd);
            GLDS(vg + kn + (size_t)32 * 1024, vd + 32 * 64);
        }

        const unsigned short* Kc = &Ks[0][0] + cur * 4096;
        const unsigned short* Vc = &Vs[0][0] + cur * 4096;

        // S init = k-mask additive term (same for all r of a j)
        float mkadd[4];
        #pragma unroll
        for (int j = 0; j < 4; ++j) mkadd[j] = mk[j] ? 0.f : NEGF;
        f32x4 s[4];
        #pragma unroll
        for (int j = 0; j < 4; ++j)
            #pragma unroll
            for (int r = 0; r < 4; ++r) s[j][r] = mkadd[j];

        __builtin_amdgcn_s_setprio(1);
        #pragma unroll
        for (int j = 0; j < 4; ++j) {
            #pragma unroll
            for (int c = 0; c < 2; ++c) {
                bf16x8 kf = *(const bf16x8*)(Kc + (j * 16 + lane16) * 64
                                             + (((c * 4 + quad) ^ (lane16 & 7)) * 8));
                s[j] = MFMA(qf[c], kf, s[j]);
            }
        }
        __builtin_amdgcn_s_setprio(0);

        // fold bias (*0.125) and q-mask
        #pragma unroll
        for (int j = 0; j < 4; ++j)
            #pragma unroll
            for (int r = 0; r < 4; ++r) {
                float v = fmaf(bfv[j][r], 0.125f, s[j][r]);
                s[j][r] = mq[r] ? v : NEGF;
            }

        // online softmax: max + rescale only (sum comes from MFMA below)
        float p[4][4];
        float alpha_r[4];
        #pragma unroll
        for (int r = 0; r < 4; ++r) {
            float mx = fmaxf(fmaxf(s[0][r], s[1][r]), fmaxf(s[2][r], s[3][r]));
            #pragma unroll
            for (int d = 1; d < 16; d <<= 1) mx = fmaxf(mx, __shfl_xor(mx, d, 64));
            float mnew = fmaxf(m_i[r], mx);
            float alpha = __expf(m_i[r] - mnew);
            m_i[r] = mnew;
            alpha_r[r] = alpha;
            #pragma unroll
            for (int j = 0; j < 4; ++j) p[j][r] = __expf(s[j][r] - mnew);
            #pragma unroll
            for (int jd = 0; jd < 4; ++jd) o[jd][r] *= alpha;
        }

        // P: C-layout -> LDS (XOR-swizzled stride-64) -> A-layout (intra-wave)
        #pragma unroll
        for (int j = 0; j < 4; ++j)
            #pragma unroll
            for (int r = 0; r < 4; ++r) {
                int row = quad * 4 + r;
                int cb = (j * 16 + lane16) * 2;
                *(unsigned short*)(psb + row * 128 + (cb ^ ((row & 7) << 4))) = f2bf(p[j][r]);
            }
        asm volatile("" ::: "memory");

        bf16x8 pf[2];
        #pragma unroll
        for (int c = 0; c < 2; ++c) {
            int cb = c * 64 + quad * 16;
            pf[c] = *(const bf16x8*)(psb + lane16 * 128 + (cb ^ ((lane16 & 7) << 4)));
        }

        // O += P V ; row-sum via ones-MFMA (D row = quad*4+r matches l_i[r])
        f32x4 lacc = zero;
        __builtin_amdgcn_s_setprio(1);
        #pragma unroll
        for (int jd = 0; jd < 4; ++jd)
            #pragma unroll
            for (int c = 0; c < 2; ++c) {
                bf16x8 vf = *(const bf16x8*)(Vc + (jd * 16 + lane16) * 64
                                             + (((c * 4 + quad) ^ (lane16 & 7)) * 8));
                o[jd] = MFMA(pf[c], vf, o[jd]);
            }
        #pragma unroll
        for (int c = 0; c < 2; ++c)
            lacc = MFMA(pf[c], ones, lacc);
        __builtin_amdgcn_s_setprio(0);

        #pragma unroll
        for (int r = 0; r < 4; ++r)
            l_i[r] = l_i[r] * alpha_r[r] + lacc[r];

        bt += 1024;   // next k-tile of bias
        // no trailing barrier: next top-barrier protects buffer reuse
    }

    float inv[4];
    #pragma unroll
    for (int r = 0; r < 4; ++r) inv[r] = 1.0f / l_i[r];

    #pragma unroll
    for (int jd = 0; jd < 4; ++jd)
        #pragma unroll
        for (int r = 0; r < 4; ++r)
            Xp[(size_t)(b * 1024 + qrow0 + quad * 4 + r) * 1024
               + h * 64 + jd * 16 + lane16] = f2bf(o[jd][r] * inv[r]);
}

// ---------------------------------------------------------------------------
// O-projection GEMM, 128x64 tile -> 512 blocks (2 blocks/CU).
// C[4096,1024] f32 = X(bf16) @ W^T + b. 4 waves as 2x2 of 64x32.
// ---------------------------------------------------------------------------
__global__ __launch_bounds__(256, 2) void gemm_o64(
    const unsigned short* __restrict__ X, const unsigned short* __restrict__ W,
    const float* __restrict__ bvec, float* __restrict__ Y)
{
    __shared__ unsigned short As[128 * 32];
    __shared__ unsigned short Bs[64 * 32];

    const int t = threadIdx.x;
    const int w = t >> 6, l = t & 63;
    const int lane16 = l & 15, quad = l >> 4;
    const int m0 = blockIdx.y * 128, n0 = blockIdx.x * 64;
    const int wr = w >> 1, wc = w & 1;

    const int srow = w * 16 + (l >> 2);                 // 0..63
    const unsigned short* agp = X + (size_t)(m0 + srow) * 1024 + (l & 3) * 8;
    const unsigned short* bgp = W + (size_t)(n0 + srow) * 1024 + (l & 3) * 8;
    unsigned short* alp = As + w * 512 + l * 8;
    unsigned short* blp = Bs + w * 512 + l * 8;

    f32x4 zero = {0.f, 0.f, 0.f, 0.f};
    f32x4 acc[4][2];
    #pragma unroll
    for (int i = 0; i < 4; ++i)
        #pragma unroll
        for (int j = 0; j < 2; ++j) acc[i][j] = zero;

    for (int kt = 0; kt < 1024; kt += 32) {
        GLDS(agp + kt, alp);
        GLDS(agp + kt + 64 * 1024, alp + 2048);
        GLDS(bgp + kt, blp);
        __syncthreads();

        bf16x8 af[4], bfv[2];
        #pragma unroll
        for (int i = 0; i < 4; ++i)
            af[i] = *(const bf16x8*)(As + (wr * 64 + i * 16 + lane16) * 32 + quad * 8);
        #pragma unroll
        for (int j = 0; j < 2; ++j)
            bfv[j] = *(const bf16x8*)(Bs + (wc * 32 + j * 16 + lane16) * 32 + quad * 8);

        #pragma unroll
        for (int i = 0; i < 4; ++i)
            #pragma unroll
            for (int j = 0; j < 2; ++j)
                acc[i][j] = MFMA(af[i], bfv[j], acc[i][j]);
        __syncthreads();
    }

    float bvl[2];
    #pragma unroll
    for (int j = 0; j < 2; ++j) bvl[j] = bvec[n0 + wc * 32 + j * 16 + lane16];

    #pragma unroll
    for (int i = 0; i < 4; ++i)
        #pragma unroll
        for (int j = 0; j < 2; ++j) {
            int n = n0 + wc * 32 + j * 16 + lane16;
            #pragma unroll
            for (int r = 0; r < 4; ++r) {
                size_t m = m0 + wr * 64 + i * 16 + quad * 4 + r;
                Y[m * 1024 + n] = acc[i][j][r] + bvl[j];
            }
        }
}

// ---------------------------------------------------------------------------
extern "C" void kernel_launch(void* const* d_in, const int* in_sizes, int n_in,
                              void* d_out, int out_size, void* d_ws, size_t ws_size,
                              hipStream_t stream)
{
    const float* query = (const float*)d_in[0];
    const float* key   = (const float*)d_in[1];
    const float* value = (const float*)d_in[2];
    const float* abias = (const float*)d_in[3];
    const int*   mask  = (const int*)d_in[4];
    const float* Wq = (const float*)d_in[5];
    const float* bq = (const float*)d_in[6];
    const float* Wk = (const float*)d_in[7];
    const float* bk = (const float*)d_in[8];
    const float* Wv = (const float*)d_in[9];
    const float* bv = (const float*)d_in[10];
    const float* Wo = (const float*)d_in[11];
    const float* bo = (const float*)d_in[12];
    float* out = (float*)d_out;

    const size_t T = (size_t)B_ * S_ * D_;           // 4 Mi
    const size_t WSZ = (size_t)D_ * D_;              // 1 Mi
    unsigned short* p = (unsigned short*)d_ws;
    unsigned short* qb  = p;  p += T;
    unsigned short* kb  = p;  p += T;
    unsigned short* vb  = p;  p += T;
    unsigned short* wqb = p;  p += WSZ;
    unsigned short* wkb = p;  p += WSZ;
    unsigned short* wvb = p;  p += WSZ;
    unsigned short* wob = p;  p += WSZ;
    unsigned short* Qpj = p;  p += T;
    unsigned short* Kpj = p;  p += T;
    unsigned short* VpT = p;  p += T;
    unsigned short* Xpj = p;  p += T;

    cvt_all<<<dim3(16384), 256, 0, stream>>>(
        query, key, value, Wq, Wk, Wv, Wo,
        qb, kb, vb, wqb, wkb, wvb, wob);

    gemm128<<<dim3(8, 32, 3), 256, 0, stream>>>(
        qb, kb, vb, wqb, wkb, wvb, bq, bk, bv,
        Qpj, Kpj, VpT, mask);

    attn_mfma<<<dim3(1024), 256, 0, stream>>>(Qpj, Kpj, VpT, abias, mask, Xpj);

    gemm_o64<<<dim3(16, 32), 256, 0, stream>>>(Xpj, wob, bo, out);
}

// Round 6
// 559.555 us; speedup vs baseline: 1.1992x; 1.1992x over previous
//
#include <hip/hip_runtime.h>
#include <hip/hip_bf16.h>
#include <math.h>

#define B_ 4
#define S_ 1024
#define D_ 1024
#define H_ 16
#define DK_ 64

typedef short bf16x8 __attribute__((ext_vector_type(8)));
typedef float f32x4 __attribute__((ext_vector_type(4)));

#define MFMA(a, b, c) __builtin_amdgcn_mfma_f32_16x16x32_bf16(a, b, c, 0, 0, 0)

// async global->LDS, 16B per lane. Effective LDS dest = wave-uniform base + lane*16.
#define GLDS(gp, lp)                                                        \
    __builtin_amdgcn_global_load_lds(                                       \
        (const __attribute__((address_space(1))) void*)(const void*)(gp),   \
        (__attribute__((address_space(3))) void*)(void*)(lp), 16, 0, 0)

static __device__ __forceinline__ unsigned short f2bf(float f) {
    __hip_bfloat16 h = __float2bfloat16(f);
    return *reinterpret_cast<unsigned short*>(&h);
}
static __device__ __forceinline__ float bf2f(unsigned short u) {
    unsigned int x = ((unsigned int)u) << 16;
    union { unsigned int i; float f; } c; c.i = x; return c.f;
}

// ---------------------------------------------------------------------------
// fused f32->bf16 converts: 3 activations (12288 blocks) + 4 weights (4096)
// ---------------------------------------------------------------------------
__global__ __launch_bounds__(256) void cvt_all(
    const float* __restrict__ a, const float* __restrict__ b, const float* __restrict__ c,
    const float* __restrict__ wa, const float* __restrict__ wb,
    const float* __restrict__ wc, const float* __restrict__ wd,
    unsigned short* __restrict__ oa, unsigned short* __restrict__ ob, unsigned short* __restrict__ oc,
    unsigned short* __restrict__ owa, unsigned short* __restrict__ owb,
    unsigned short* __restrict__ owc, unsigned short* __restrict__ owd)
{
    int bx = blockIdx.x;
    const float* in; unsigned short* out; int i;
    if (bx < 12288) {
        int which = bx >> 12;
        in  = which == 0 ? a : which == 1 ? b : c;
        out = which == 0 ? oa : which == 1 ? ob : oc;
        i = (bx & 4095) * 256 + threadIdx.x;
    } else {
        int b2 = bx - 12288;
        int which = b2 >> 10;
        in  = which == 0 ? wa : which == 1 ? wb : which == 2 ? wc : wd;
        out = which == 0 ? owa : which == 1 ? owb : which == 2 ? owc : owd;
        i = (b2 & 1023) * 256 + threadIdx.x;
    }
    float4 v = ((const float4*)in)[i];
    ushort4 o;
    o.x = f2bf(v.x); o.y = f2bf(v.y); o.z = f2bf(v.z); o.w = f2bf(v.w);
    ((ushort4*)out)[i] = o;
}

// ---------------------------------------------------------------------------
// bias prep (standalone, coalesced transpose — streaming raw bias in attn was
// a measured 3.2x over-fetch + latency regression; this stays).
// [B,S,S,H] f32 -> bf16 C-fragment-ordered tiles, with mask + /8 folded in.
// ---------------------------------------------------------------------------
__global__ __launch_bounds__(256) void prep_bias(
    const float* __restrict__ bias, const int* __restrict__ mask,
    unsigned short* __restrict__ biasP)
{
    const int t = threadIdx.x;
    const int h = t & 15, u = t >> 4;
    const int x = blockIdx.x;
    const int kt = x & 15, q16 = (x >> 4) & 63, b = x >> 10;

    const unsigned short NEG = f2bf(-28672.f);

    int mk[4];
    #pragma unroll
    for (int j = 0; j < 4; ++j) mk[j] = mask[b * 1024 + kt * 64 + j * 16 + u];

    const float* bb = bias + (((size_t)(b * 1024 + q16 * 16) * 1024) + kt * 64) * 16 + h;
    unsigned short* ob = biasP + ((((size_t)(b * 16 + h) * 64 + q16) * 16 + kt) * 64) * 16;

    #pragma unroll
    for (int quad = 0; quad < 4; ++quad) {
        bf16x8 v0, v1;
        #pragma unroll
        for (int r = 0; r < 4; ++r) {
            int q = quad * 4 + r;
            int mq = mask[b * 1024 + q16 * 16 + q];  // wave-uniform -> s_load
            #pragma unroll
            for (int j = 0; j < 4; ++j) {
                float v = bb[((size_t)q * 1024 + j * 16 + u) * 16];
                unsigned short pv = (mq && mk[j]) ? f2bf(v * 0.125f) : NEG;
                if (j < 2) v0[j * 4 + r] = (short)pv;
                else       v1[(j - 2) * 4 + r] = (short)pv;
            }
        }
        unsigned short* dst = ob + (size_t)(quad * 16 + u) * 16;
        *(bf16x8*)(dst) = v0;
        *(bf16x8*)(dst + 8) = v1;
    }
}

// ---------------------------------------------------------------------------
// m97-shape bf16 MFMA GEMM for QKV projections: C[4096,1024] = X @ W^T + bvec.
// Tile 128x128, BK=32, 4 waves of 64x64. blockIdx.z selects (X,W,b,Y).
// z=0: Q-proj -> bf16, *0.125, zero masked rows
// z=1: K-proj -> bf16 row-major
// z=2: V-proj -> bf16 transposed [(b*1024+n)][s]
// ---------------------------------------------------------------------------
__global__ __launch_bounds__(256, 2) void gemm128(
    const unsigned short* __restrict__ X0, const unsigned short* __restrict__ X1,
    const unsigned short* __restrict__ X2,
    const unsigned short* __restrict__ W0, const unsigned short* __restrict__ W1,
    const unsigned short* __restrict__ W2,
    const float* __restrict__ bv0, const float* __restrict__ bv1,
    const float* __restrict__ bv2,
    unsigned short* __restrict__ Y0, unsigned short* __restrict__ Y1,
    unsigned short* __restrict__ Y2,
    const int* __restrict__ mask)
{
    __shared__ unsigned short As[128 * 32];
    __shared__ unsigned short Bs[128 * 32];

    const int z = blockIdx.z;
    const unsigned short* X = z == 0 ? X0 : z == 1 ? X1 : X2;
    const unsigned short* W = z == 0 ? W0 : z == 1 ? W1 : W2;
    const float* bvec = z == 0 ? bv0 : z == 1 ? bv1 : bv2;
    unsigned short* Y = z == 0 ? Y0 : z == 1 ? Y1 : Y2;

    const int t = threadIdx.x;
    const int w = t >> 6, l = t & 63;
    const int lane16 = l & 15, quad = l >> 4;
    const int m0 = blockIdx.y * 128, n0 = blockIdx.x * 128;
    const int wr = w >> 1, wc = w & 1;

    const int srow = w * 16 + (l >> 2);
    const unsigned short* agp = X + (size_t)(m0 + srow) * 1024 + (l & 3) * 8;
    const unsigned short* bgp = W + (size_t)(n0 + srow) * 1024 + (l & 3) * 8;
    unsigned short* alp = As + w * 512 + l * 8;
    unsigned short* blp = Bs + w * 512 + l * 8;

    f32x4 zero = {0.f, 0.f, 0.f, 0.f};
    f32x4 acc[4][4];
    #pragma unroll
    for (int i = 0; i < 4; ++i)
        #pragma unroll
        for (int j = 0; j < 4; ++j) acc[i][j] = zero;

    for (int kt = 0; kt < 1024; kt += 32) {
        GLDS(agp + kt, alp);
        GLDS(agp + kt + 64 * 1024, alp + 2048);
        GLDS(bgp + kt, blp);
        GLDS(bgp + kt + 64 * 1024, blp + 2048);
        __syncthreads();

        bf16x8 af[4], bfv[4];
        #pragma unroll
        for (int i = 0; i < 4; ++i)
            af[i] = *(const bf16x8*)(As + (wr * 64 + i * 16 + lane16) * 32 + quad * 8);
        #pragma unroll
        for (int j = 0; j < 4; ++j)
            bfv[j] = *(const bf16x8*)(Bs + (wc * 64 + j * 16 + lane16) * 32 + quad * 8);

        #pragma unroll
        for (int i = 0; i < 4; ++i)
            #pragma unroll
            for (int j = 0; j < 4; ++j)
                acc[i][j] = MFMA(af[i], bfv[j], acc[i][j]);
        __syncthreads();
    }

    float bvl[4];
    #pragma unroll
    for (int j = 0; j < 4; ++j) bvl[j] = bvec[n0 + wc * 64 + j * 16 + lane16];

    if (z == 2) {
        // V transposed: out[(b*1024+n)][s], pack 4 consecutive s
        const int bb = m0 >> 10;
        const int sb = (m0 & 1023) + wr * 64;
        #pragma unroll
        for (int i = 0; i < 4; ++i) {
            #pragma unroll
            for (int j = 0; j < 4; ++j) {
                int n = n0 + wc * 64 + j * 16 + lane16;
                ushort4 pk;
                pk.x = f2bf(acc[i][j][0] + bvl[j]);
                pk.y = f2bf(acc[i][j][1] + bvl[j]);
                pk.z = f2bf(acc[i][j][2] + bvl[j]);
                pk.w = f2bf(acc[i][j][3] + bvl[j]);
                int s = sb + i * 16 + quad * 4;
                *(ushort4*)(Y + ((size_t)(bb * 1024 + n)) * 1024 + s) = pk;
            }
        }
    } else {
        #pragma unroll
        for (int i = 0; i < 4; ++i) {
            int mrow[4];
            #pragma unroll
            for (int r = 0; r < 4; ++r)
                mrow[r] = (z == 0) ? mask[m0 + wr * 64 + i * 16 + quad * 4 + r] : 1;
            #pragma unroll
            for (int j = 0; j < 4; ++j) {
                int n = n0 + wc * 64 + j * 16 + lane16;
                #pragma unroll
                for (int r = 0; r < 4; ++r) {
                    size_t m = m0 + wr * 64 + i * 16 + quad * 4 + r;
                    float val = acc[i][j][r] + bvl[j];
                    if (z == 0) val = mrow[r] ? val * 0.125f : 0.f;
                    Y[m * 1024 + n] = f2bf(val);
                }
            }
        }
    }
}

// ---------------------------------------------------------------------------
// MFMA flash attention. This round: 128-q blocks (512 blocks, 32 q/wave as
// two 16-row MFMA tiles i=0,1). Per phase: 36 MFMA vs 18, same staging, same
// barriers -> barrier-drain count halves, K/V HBM re-reads halve, K/V LDS
// fragments reused across both row-tiles. LDS = 32K K/V dbuf + 16K Ps = 48 KB
// (grid is 2 blocks/CU anyway). Bias via prepped biasP (coalesced).
// bid = qt2*64 + bh keeps all q-tiles of a (b,h) on one XCD class.
// ---------------------------------------------------------------------------
__global__ __launch_bounds__(256, 2) void attn_mfma(
    const unsigned short* __restrict__ Qp, const unsigned short* __restrict__ Kp,
    const unsigned short* __restrict__ VpT, const unsigned short* __restrict__ biasP,
    unsigned short* __restrict__ Xp)
{
    __shared__ unsigned short Ks[2][64 * 64];
    __shared__ unsigned short Vs[2][64 * 64];
    __shared__ unsigned short Ps[4][2][16 * 64];

    const int t = threadIdx.x;
    const int w = t >> 6, l = t & 63;
    const int lane16 = l & 15, quad = l >> 4;

    const int bid = blockIdx.x;          // 512 = 8 qt2 * 64 bh
    const int bh = bid & 63, qt2 = bid >> 6;
    const int h = bh & 15, b = bh >> 4;
    const int qrow0 = qt2 * 128 + w * 32;     // wave owns rows [qrow0, qrow0+32)

    // Q fragments (bf16, pre-scaled by 0.125; masked rows zeroed), 2 row-tiles
    bf16x8 qf[2][2];
    #pragma unroll
    for (int i = 0; i < 2; ++i)
        #pragma unroll
        for (int c = 0; c < 2; ++c)
            qf[i][c] = *(const bf16x8*)(Qp + (size_t)(b * 1024 + qrow0 + i * 16 + lane16) * 1024
                                        + h * 64 + c * 32 + quad * 8);

    // all-ones bf16 fragment for row-sum MFMA
    bf16x8 ones;
    #pragma unroll
    for (int e = 0; e < 8; ++e) ones[e] = (short)0x3F80;

    // bias fragment bases, one per row-tile (q16 = qt2*8 + w*2 + i)
    const unsigned short* bp[2];
    #pragma unroll
    for (int i = 0; i < 2; ++i)
        bp[i] = biasP + ((((size_t)(b * 16 + h) * 64 + (qt2 * 8 + w * 2 + i)) * 16) * 64 + l) * 16;

    // K/V staging (xor-swizzled 16B granules within 128B rows)
    const int krow = w * 8 + (l >> 3);
    const int kgran = (l & 7) ^ ((l >> 3) & 7);
    const unsigned short* kg = Kp + (size_t)(b * 1024 + krow) * 1024 + h * 64 + kgran * 8;
    const unsigned short* vg = VpT + ((size_t)(b * 16 + h) * 64 + krow) * 1024 + kgran * 8;
    unsigned short* kst = &Ks[0][w * 512 + l * 8];
    unsigned short* vst = &Vs[0][w * 512 + l * 8];

    // prologue: stage tile 0 into buffer 0, load bias frags for tile 0
    GLDS(kg, kst);
    GLDS(kg + (size_t)32 * 1024, kst + 32 * 64);
    GLDS(vg, vst);
    GLDS(vg + (size_t)32 * 1024, vst + 32 * 64);
    bf16x8 bfr[2][2];
    #pragma unroll
    for (int i = 0; i < 2; ++i) {
        bfr[i][0] = *(const bf16x8*)(bp[i]);
        bfr[i][1] = *(const bf16x8*)(bp[i] + 8);
    }

    f32x4 zero = {0.f, 0.f, 0.f, 0.f};
    f32x4 o[2][4];
    #pragma unroll
    for (int i = 0; i < 2; ++i)
        #pragma unroll
        for (int j = 0; j < 4; ++j) o[i][j] = zero;
    float m_i[2][4], l_i[2][4];
    #pragma unroll
    for (int i = 0; i < 2; ++i)
        #pragma unroll
        for (int r = 0; r < 4; ++r) { m_i[i][r] = -1e30f; l_i[i][r] = 0.f; }

    for (int kt16 = 0; kt16 < 16; ++kt16) {
        const int cur = kt16 & 1;
        __syncthreads();    // publishes tile kt16 (drains in-flight prefetch)

        // prefetch tile kt16+1 into the other buffer (uniform branch)
        if (kt16 < 15) {
            const size_t kn = (size_t)(kt16 + 1) * 64;
            unsigned short* kd = kst + (cur ^ 1) * 4096;
            unsigned short* vd = vst + (cur ^ 1) * 4096;
            GLDS(kg + kn * 1024, kd);
            GLDS(kg + (kn + 32) * 1024, kd + 32 * 64);
            GLDS(vg + kn, vd);
            GLDS(vg + kn + (size_t)32 * 1024, vd + 32 * 64);
        }

        const unsigned short* Kc = &Ks[0][0] + cur * 4096;
        const unsigned short* Vc = &Vs[0][0] + cur * 4096;

        // S = bias + Q K^T (bias as accumulator init), both row-tiles
        f32x4 s[2][4];
        #pragma unroll
        for (int i = 0; i < 2; ++i)
            #pragma unroll
            for (int j = 0; j < 2; ++j)
                #pragma unroll
                for (int r = 0; r < 4; ++r) {
                    s[i][j][r]     = bf2f((unsigned short)bfr[i][0][j * 4 + r]);
                    s[i][2 + j][r] = bf2f((unsigned short)bfr[i][1][j * 4 + r]);
                }

        __builtin_amdgcn_s_setprio(1);
        #pragma unroll
        for (int j = 0; j < 4; ++j) {
            #pragma unroll
            for (int c = 0; c < 2; ++c) {
                bf16x8 kf = *(const bf16x8*)(Kc + (j * 16 + lane16) * 64
                                             + (((c * 4 + quad) ^ (lane16 & 7)) * 8));
                #pragma unroll
                for (int i = 0; i < 2; ++i)
                    s[i][j] = MFMA(qf[i][c], kf, s[i][j]);
            }
        }
        __builtin_amdgcn_s_setprio(0);

        // prefetch bias fragments for next tile (bfr consumed above)
        if (kt16 < 15) {
            #pragma unroll
            for (int i = 0; i < 2; ++i) {
                bfr[i][0] = *(const bf16x8*)(bp[i] + (size_t)(kt16 + 1) * 1024);
                bfr[i][1] = *(const bf16x8*)(bp[i] + (size_t)(kt16 + 1) * 1024 + 8);
            }
        }

        // online softmax per row-tile: max + rescale (sum via ones-MFMA below)
        float p[2][4][4];
        float alpha_r[2][4];
        #pragma unroll
        for (int i = 0; i < 2; ++i)
            #pragma unroll
            for (int r = 0; r < 4; ++r) {
                float mx = fmaxf(fmaxf(s[i][0][r], s[i][1][r]), fmaxf(s[i][2][r], s[i][3][r]));
                #pragma unroll
                for (int d = 1; d < 16; d <<= 1) mx = fmaxf(mx, __shfl_xor(mx, d, 64));
                float mnew = fmaxf(m_i[i][r], mx);
                float alpha = __expf(m_i[i][r] - mnew);
                m_i[i][r] = mnew;
                alpha_r[i][r] = alpha;
                #pragma unroll
                for (int j = 0; j < 4; ++j) p[i][j][r] = __expf(s[i][j][r] - mnew);
                #pragma unroll
                for (int jd = 0; jd < 4; ++jd) o[i][jd][r] *= alpha;
            }

        // P: C-layout -> LDS (XOR-swizzled stride-64, per (wave,row-tile) buf)
        #pragma unroll
        for (int i = 0; i < 2; ++i) {
            char* psb = (char*)&Ps[w][i][0];
            #pragma unroll
            for (int j = 0; j < 4; ++j)
                #pragma unroll
                for (int r = 0; r < 4; ++r) {
                    int row = quad * 4 + r;
                    int cb = (j * 16 + lane16) * 2;
                    *(unsigned short*)(psb + row * 128 + (cb ^ ((row & 7) << 4))) = f2bf(p[i][j][r]);
                }
        }
        asm volatile("" ::: "memory");

        bf16x8 pf[2][2];
        #pragma unroll
        for (int i = 0; i < 2; ++i) {
            char* psb = (char*)&Ps[w][i][0];
            #pragma unroll
            for (int c = 0; c < 2; ++c) {
                int cb = c * 64 + quad * 16;
                pf[i][c] = *(const bf16x8*)(psb + lane16 * 128 + (cb ^ ((lane16 & 7) << 4)));
            }
        }

        // O += P V ; V fragments shared across row-tiles
        f32x4 lacc[2] = {zero, zero};
        __builtin_amdgcn_s_setprio(1);
        #pragma unroll
        for (int jd = 0; jd < 4; ++jd)
            #pragma unroll
            for (int c = 0; c < 2; ++c) {
                bf16x8 vf = *(const bf16x8*)(Vc + (jd * 16 + lane16) * 64
                                             + (((c * 4 + quad) ^ (lane16 & 7)) * 8));
                #pragma unroll
                for (int i = 0; i < 2; ++i)
                    o[i][jd] = MFMA(pf[i][c], vf, o[i][jd]);
            }
        #pragma unroll
        for (int i = 0; i < 2; ++i)
            #pragma unroll
            for (int c = 0; c < 2; ++c)
                lacc[i] = MFMA(pf[i][c], ones, lacc[i]);
        __builtin_amdgcn_s_setprio(0);

        #pragma unroll
        for (int i = 0; i < 2; ++i)
            #pragma unroll
            for (int r = 0; r < 4; ++r)
                l_i[i][r] = l_i[i][r] * alpha_r[i][r] + lacc[i][r];
        // no trailing barrier: next top-barrier protects buffer reuse
    }

    #pragma unroll
    for (int i = 0; i < 2; ++i) {
        float inv[4];
        #pragma unroll
        for (int r = 0; r < 4; ++r) inv[r] = 1.0f / l_i[i][r];
        #pragma unroll
        for (int jd = 0; jd < 4; ++jd)
            #pragma unroll
            for (int r = 0; r < 4; ++r)
                Xp[(size_t)(b * 1024 + qrow0 + i * 16 + quad * 4 + r) * 1024
                   + h * 64 + jd * 16 + lane16] = f2bf(o[i][jd][r] * inv[r]);
    }
}

// ---------------------------------------------------------------------------
// O-projection GEMM, 128x64 tile -> 512 blocks (2 blocks/CU).
// C[4096,1024] f32 = X(bf16) @ W^T + b. 4 waves as 2x2 of 64x32.
// ---------------------------------------------------------------------------
__global__ __launch_bounds__(256, 2) void gemm_o64(
    const unsigned short* __restrict__ X, const unsigned short* __restrict__ W,
    const float* __restrict__ bvec, float* __restrict__ Y)
{
    __shared__ unsigned short As[128 * 32];
    __shared__ unsigned short Bs[64 * 32];

    const int t = threadIdx.x;
    const int w = t >> 6, l = t & 63;
    const int lane16 = l & 15, quad = l >> 4;
    const int m0 = blockIdx.y * 128, n0 = blockIdx.x * 64;
    const int wr = w >> 1, wc = w & 1;

    const int srow = w * 16 + (l >> 2);                 // 0..63
    const unsigned short* agp = X + (size_t)(m0 + srow) * 1024 + (l & 3) * 8;
    const unsigned short* bgp = W + (size_t)(n0 + srow) * 1024 + (l & 3) * 8;
    unsigned short* alp = As + w * 512 + l * 8;
    unsigned short* blp = Bs + w * 512 + l * 8;

    f32x4 zero = {0.f, 0.f, 0.f, 0.f};
    f32x4 acc[4][2];
    #pragma unroll
    for (int i = 0; i < 4; ++i)
        #pragma unroll
        for (int j = 0; j < 2; ++j) acc[i][j] = zero;

    for (int kt = 0; kt < 1024; kt += 32) {
        GLDS(agp + kt, alp);
        GLDS(agp + kt + 64 * 1024, alp + 2048);
        GLDS(bgp + kt, blp);
        __syncthreads();

        bf16x8 af[4], bfv[2];
        #pragma unroll
        for (int i = 0; i < 4; ++i)
            af[i] = *(const bf16x8*)(As + (wr * 64 + i * 16 + lane16) * 32 + quad * 8);
        #pragma unroll
        for (int j = 0; j < 2; ++j)
            bfv[j] = *(const bf16x8*)(Bs + (wc * 32 + j * 16 + lane16) * 32 + quad * 8);

        #pragma unroll
        for (int i = 0; i < 4; ++i)
            #pragma unroll
            for (int j = 0; j < 2; ++j)
                acc[i][j] = MFMA(af[i], bfv[j], acc[i][j]);
        __syncthreads();
    }

    float bvl[2];
    #pragma unroll
    for (int j = 0; j < 2; ++j) bvl[j] = bvec[n0 + wc * 32 + j * 16 + lane16];

    #pragma unroll
    for (int i = 0; i < 4; ++i)
        #pragma unroll
        for (int j = 0; j < 2; ++j) {
            int n = n0 + wc * 32 + j * 16 + lane16;
            #pragma unroll
            for (int r = 0; r < 4; ++r) {
                size_t m = m0 + wr * 64 + i * 16 + quad * 4 + r;
                Y[m * 1024 + n] = acc[i][j][r] + bvl[j];
            }
        }
}

// ---------------------------------------------------------------------------
extern "C" void kernel_launch(void* const* d_in, const int* in_sizes, int n_in,
                              void* d_out, int out_size, void* d_ws, size_t ws_size,
                              hipStream_t stream)
{
    const float* query = (const float*)d_in[0];
    const float* key   = (const float*)d_in[1];
    const float* value = (const float*)d_in[2];
    const float* abias = (const float*)d_in[3];
    const int*   mask  = (const int*)d_in[4];
    const float* Wq = (const float*)d_in[5];
    const float* bq = (const float*)d_in[6];
    const float* Wk = (const float*)d_in[7];
    const float* bk = (const float*)d_in[8];
    const float* Wv = (const float*)d_in[9];
    const float* bv = (const float*)d_in[10];
    const float* Wo = (const float*)d_in[11];
    const float* bo = (const float*)d_in[12];
    float* out = (float*)d_out;

    const size_t T = (size_t)B_ * S_ * D_;           // 4 Mi
    const size_t WSZ = (size_t)D_ * D_;              // 1 Mi
    const size_t BPSZ = (size_t)B_ * H_ * S_ * S_;   // 64 Mi
    unsigned short* p = (unsigned short*)d_ws;
    unsigned short* biasP = p;  p += BPSZ;
    unsigned short* qb  = p;  p += T;
    unsigned short* kb  = p;  p += T;
    unsigned short* vb  = p;  p += T;
    unsigned short* wqb = p;  p += WSZ;
    unsigned short* wkb = p;  p += WSZ;
    unsigned short* wvb = p;  p += WSZ;
    unsigned short* wob = p;  p += WSZ;
    unsigned short* Qpj = p;  p += T;
    unsigned short* Kpj = p;  p += T;
    unsigned short* VpT = p;  p += T;
    unsigned short* Xpj = p;  p += T;

    cvt_all<<<dim3(16384), 256, 0, stream>>>(
        query, key, value, Wq, Wk, Wv, Wo,
        qb, kb, vb, wqb, wkb, wvb, wob);

    prep_bias<<<dim3(4096), 256, 0, stream>>>(abias, mask, biasP);

    gemm128<<<dim3(8, 32, 3), 256, 0, stream>>>(
        qb, kb, vb, wqb, wkb, wvb, bq, bk, bv,
        Qpj, Kpj, VpT, mask);

    attn_mfma<<<dim3(512), 256, 0, stream>>>(Qpj, Kpj, VpT, biasP, Xpj);

    gemm_o64<<<dim3(16, 32), 256, 0, stream>>>(Xpj, wob, bo, out);
}

// Round 7
// 558.589 us; speedup vs baseline: 1.2013x; 1.0017x over previous
//
#include <hip/hip_runtime.h>
#include <hip/hip_bf16.h>
#include <math.h>

#define B_ 4
#define S_ 1024
#define D_ 1024
#define H_ 16
#define DK_ 64

typedef short bf16x8 __attribute__((ext_vector_type(8)));
typedef float f32x4 __attribute__((ext_vector_type(4)));

#define MFMA(a, b, c) __builtin_amdgcn_mfma_f32_16x16x32_bf16(a, b, c, 0, 0, 0)

// async global->LDS, 16B per lane. Effective LDS dest = wave-uniform base + lane*16.
#define GLDS(gp, lp)                                                        \
    __builtin_amdgcn_global_load_lds(                                       \
        (const __attribute__((address_space(1))) void*)(const void*)(gp),   \
        (__attribute__((address_space(3))) void*)(void*)(lp), 16, 0, 0)

static __device__ __forceinline__ unsigned short f2bf(float f) {
    __hip_bfloat16 h = __float2bfloat16(f);
    return *reinterpret_cast<unsigned short*>(&h);
}
static __device__ __forceinline__ float bf2f(unsigned short u) {
    unsigned int x = ((unsigned int)u) << 16;
    union { unsigned int i; float f; } c; c.i = x; return c.f;
}

// ---------------------------------------------------------------------------
// fused f32->bf16 converts: 3 activations (12288 blocks) + 4 weights (4096)
// ---------------------------------------------------------------------------
__global__ __launch_bounds__(256) void cvt_all(
    const float* __restrict__ a, const float* __restrict__ b, const float* __restrict__ c,
    const float* __restrict__ wa, const float* __restrict__ wb,
    const float* __restrict__ wc, const float* __restrict__ wd,
    unsigned short* __restrict__ oa, unsigned short* __restrict__ ob, unsigned short* __restrict__ oc,
    unsigned short* __restrict__ owa, unsigned short* __restrict__ owb,
    unsigned short* __restrict__ owc, unsigned short* __restrict__ owd)
{
    int bx = blockIdx.x;
    const float* in; unsigned short* out; int i;
    if (bx < 12288) {
        int which = bx >> 12;
        in  = which == 0 ? a : which == 1 ? b : c;
        out = which == 0 ? oa : which == 1 ? ob : oc;
        i = (bx & 4095) * 256 + threadIdx.x;
    } else {
        int b2 = bx - 12288;
        int which = b2 >> 10;
        in  = which == 0 ? wa : which == 1 ? wb : which == 2 ? wc : wd;
        out = which == 0 ? owa : which == 1 ? owb : which == 2 ? owc : owd;
        i = (b2 & 1023) * 256 + threadIdx.x;
    }
    float4 v = ((const float4*)in)[i];
    ushort4 o;
    o.x = f2bf(v.x); o.y = f2bf(v.y); o.z = f2bf(v.z); o.w = f2bf(v.w);
    ((ushort4*)out)[i] = o;
}

// ---------------------------------------------------------------------------
// bias prep (standalone, coalesced transpose).
// [B,S,S,H] f32 -> bf16 C-fragment-ordered tiles, with mask + /8 folded in.
// ---------------------------------------------------------------------------
__global__ __launch_bounds__(256) void prep_bias(
    const float* __restrict__ bias, const int* __restrict__ mask,
    unsigned short* __restrict__ biasP)
{
    const int t = threadIdx.x;
    const int h = t & 15, u = t >> 4;
    const int x = blockIdx.x;
    const int kt = x & 15, q16 = (x >> 4) & 63, b = x >> 10;

    const unsigned short NEG = f2bf(-28672.f);

    int mk[4];
    #pragma unroll
    for (int j = 0; j < 4; ++j) mk[j] = mask[b * 1024 + kt * 64 + j * 16 + u];

    const float* bb = bias + (((size_t)(b * 1024 + q16 * 16) * 1024) + kt * 64) * 16 + h;
    unsigned short* ob = biasP + ((((size_t)(b * 16 + h) * 64 + q16) * 16 + kt) * 64) * 16;

    #pragma unroll
    for (int quad = 0; quad < 4; ++quad) {
        bf16x8 v0, v1;
        #pragma unroll
        for (int r = 0; r < 4; ++r) {
            int q = quad * 4 + r;
            int mq = mask[b * 1024 + q16 * 16 + q];  // wave-uniform -> s_load
            #pragma unroll
            for (int j = 0; j < 4; ++j) {
                float v = bb[((size_t)q * 1024 + j * 16 + u) * 16];
                unsigned short pv = (mq && mk[j]) ? f2bf(v * 0.125f) : NEG;
                if (j < 2) v0[j * 4 + r] = (short)pv;
                else       v1[(j - 2) * 4 + r] = (short)pv;
            }
        }
        unsigned short* dst = ob + (size_t)(quad * 16 + u) * 16;
        *(bf16x8*)(dst) = v0;
        *(bf16x8*)(dst + 8) = v1;
    }
}

// ---------------------------------------------------------------------------
// m97-shape bf16 MFMA GEMM for QKV projections: C[4096,1024] = X @ W^T + bvec.
// Tile 128x128, BK=32, 4 waves of 64x64. 1D grid 768, id = z*256 + n*32 + m
// so id%8 = m%8: the 8 n-blocks sharing an A-panel co-locate on one XCD
// (old 3D grid had id%8 = n -> A fetched 8x from HBM: 192 MB for an 8 MB
// tensor; this mapping makes A ~24 MB, W ~48 MB).
// z=0: Q-proj -> bf16, *0.125, zero masked rows
// z=1: K-proj -> bf16 row-major
// z=2: V-proj -> bf16 transposed [(b*1024+n)][s]
// ---------------------------------------------------------------------------
__global__ __launch_bounds__(256, 2) void gemm128(
    const unsigned short* __restrict__ X0, const unsigned short* __restrict__ X1,
    const unsigned short* __restrict__ X2,
    const unsigned short* __restrict__ W0, const unsigned short* __restrict__ W1,
    const unsigned short* __restrict__ W2,
    const float* __restrict__ bv0, const float* __restrict__ bv1,
    const float* __restrict__ bv2,
    unsigned short* __restrict__ Y0, unsigned short* __restrict__ Y1,
    unsigned short* __restrict__ Y2,
    const int* __restrict__ mask)
{
    __shared__ unsigned short As[128 * 32];
    __shared__ unsigned short Bs[128 * 32];

    const int id = blockIdx.x;
    const int z = id >> 8;
    const int rem = id & 255;
    const int n0 = (rem >> 5) * 128;       // 8 n-tiles
    const int m0 = (rem & 31) * 128;       // 32 m-tiles; id%8 = m%8 -> XCD by m

    const unsigned short* X = z == 0 ? X0 : z == 1 ? X1 : X2;
    const unsigned short* W = z == 0 ? W0 : z == 1 ? W1 : W2;
    const float* bvec = z == 0 ? bv0 : z == 1 ? bv1 : bv2;
    unsigned short* Y = z == 0 ? Y0 : z == 1 ? Y1 : Y2;

    const int t = threadIdx.x;
    const int w = t >> 6, l = t & 63;
    const int lane16 = l & 15, quad = l >> 4;
    const int wr = w >> 1, wc = w & 1;

    const int srow = w * 16 + (l >> 2);
    const unsigned short* agp = X + (size_t)(m0 + srow) * 1024 + (l & 3) * 8;
    const unsigned short* bgp = W + (size_t)(n0 + srow) * 1024 + (l & 3) * 8;
    unsigned short* alp = As + w * 512 + l * 8;
    unsigned short* blp = Bs + w * 512 + l * 8;

    f32x4 zero = {0.f, 0.f, 0.f, 0.f};
    f32x4 acc[4][4];
    #pragma unroll
    for (int i = 0; i < 4; ++i)
        #pragma unroll
        for (int j = 0; j < 4; ++j) acc[i][j] = zero;

    for (int kt = 0; kt < 1024; kt += 32) {
        GLDS(agp + kt, alp);
        GLDS(agp + kt + 64 * 1024, alp + 2048);
        GLDS(bgp + kt, blp);
        GLDS(bgp + kt + 64 * 1024, blp + 2048);
        __syncthreads();

        bf16x8 af[4], bfv[4];
        #pragma unroll
        for (int i = 0; i < 4; ++i)
            af[i] = *(const bf16x8*)(As + (wr * 64 + i * 16 + lane16) * 32 + quad * 8);
        #pragma unroll
        for (int j = 0; j < 4; ++j)
            bfv[j] = *(const bf16x8*)(Bs + (wc * 64 + j * 16 + lane16) * 32 + quad * 8);

        #pragma unroll
        for (int i = 0; i < 4; ++i)
            #pragma unroll
            for (int j = 0; j < 4; ++j)
                acc[i][j] = MFMA(af[i], bfv[j], acc[i][j]);
        __syncthreads();
    }

    float bvl[4];
    #pragma unroll
    for (int j = 0; j < 4; ++j) bvl[j] = bvec[n0 + wc * 64 + j * 16 + lane16];

    if (z == 2) {
        // V transposed: out[(b*1024+n)][s], pack 4 consecutive s
        const int bb = m0 >> 10;
        const int sb = (m0 & 1023) + wr * 64;
        #pragma unroll
        for (int i = 0; i < 4; ++i) {
            #pragma unroll
            for (int j = 0; j < 4; ++j) {
                int n = n0 + wc * 64 + j * 16 + lane16;
                ushort4 pk;
                pk.x = f2bf(acc[i][j][0] + bvl[j]);
                pk.y = f2bf(acc[i][j][1] + bvl[j]);
                pk.z = f2bf(acc[i][j][2] + bvl[j]);
                pk.w = f2bf(acc[i][j][3] + bvl[j]);
                int s = sb + i * 16 + quad * 4;
                *(ushort4*)(Y + ((size_t)(bb * 1024 + n)) * 1024 + s) = pk;
            }
        }
    } else {
        #pragma unroll
        for (int i = 0; i < 4; ++i) {
            int mrow[4];
            #pragma unroll
            for (int r = 0; r < 4; ++r)
                mrow[r] = (z == 0) ? mask[m0 + wr * 64 + i * 16 + quad * 4 + r] : 1;
            #pragma unroll
            for (int j = 0; j < 4; ++j) {
                int n = n0 + wc * 64 + j * 16 + lane16;
                #pragma unroll
                for (int r = 0; r < 4; ++r) {
                    size_t m = m0 + wr * 64 + i * 16 + quad * 4 + r;
                    float val = acc[i][j][r] + bvl[j];
                    if (z == 0) val = mrow[r] ? val * 0.125f : 0.f;
                    Y[m * 1024 + n] = f2bf(val);
                }
            }
        }
    }
}

// ---------------------------------------------------------------------------
// MFMA flash attention, 128-q blocks (512 blocks, 32 q/wave as two 16-row
// MFMA tiles). This round: single per-wave Ps buffer used sequentially per
// row-tile (in-order per-wave DS ops make it safe) -> LDS 48->40 KB, fewer
// live VGPRs -> headroom for 3-4 blocks/CU to hide the bias stream.
// bid = qt2*64 + bh keeps all q-tiles of a (b,h) on one XCD.
// ---------------------------------------------------------------------------
__global__ __launch_bounds__(256, 2) void attn_mfma(
    const unsigned short* __restrict__ Qp, const unsigned short* __restrict__ Kp,
    const unsigned short* __restrict__ VpT, const unsigned short* __restrict__ biasP,
    unsigned short* __restrict__ Xp)
{
    __shared__ unsigned short Ks[2][64 * 64];
    __shared__ unsigned short Vs[2][64 * 64];
    __shared__ unsigned short Ps[4][16 * 64];

    const int t = threadIdx.x;
    const int w = t >> 6, l = t & 63;
    const int lane16 = l & 15, quad = l >> 4;

    const int bid = blockIdx.x;          // 512 = 8 qt2 * 64 bh
    const int bh = bid & 63, qt2 = bid >> 6;
    const int h = bh & 15, b = bh >> 4;
    const int qrow0 = qt2 * 128 + w * 32;     // wave owns rows [qrow0, qrow0+32)

    // Q fragments (bf16, pre-scaled by 0.125; masked rows zeroed), 2 row-tiles
    bf16x8 qf[2][2];
    #pragma unroll
    for (int i = 0; i < 2; ++i)
        #pragma unroll
        for (int c = 0; c < 2; ++c)
            qf[i][c] = *(const bf16x8*)(Qp + (size_t)(b * 1024 + qrow0 + i * 16 + lane16) * 1024
                                        + h * 64 + c * 32 + quad * 8);

    // all-ones bf16 fragment for row-sum MFMA
    bf16x8 ones;
    #pragma unroll
    for (int e = 0; e < 8; ++e) ones[e] = (short)0x3F80;

    // bias fragment bases, one per row-tile (q16 = qt2*8 + w*2 + i)
    const unsigned short* bp[2];
    #pragma unroll
    for (int i = 0; i < 2; ++i)
        bp[i] = biasP + ((((size_t)(b * 16 + h) * 64 + (qt2 * 8 + w * 2 + i)) * 16) * 64 + l) * 16;

    // K/V staging (xor-swizzled 16B granules within 128B rows)
    const int krow = w * 8 + (l >> 3);
    const int kgran = (l & 7) ^ ((l >> 3) & 7);
    const unsigned short* kg = Kp + (size_t)(b * 1024 + krow) * 1024 + h * 64 + kgran * 8;
    const unsigned short* vg = VpT + ((size_t)(b * 16 + h) * 64 + krow) * 1024 + kgran * 8;
    unsigned short* kst = &Ks[0][w * 512 + l * 8];
    unsigned short* vst = &Vs[0][w * 512 + l * 8];

    // prologue: stage tile 0 into buffer 0, load bias frags for tile 0
    GLDS(kg, kst);
    GLDS(kg + (size_t)32 * 1024, kst + 32 * 64);
    GLDS(vg, vst);
    GLDS(vg + (size_t)32 * 1024, vst + 32 * 64);
    bf16x8 bfr[2][2];
    #pragma unroll
    for (int i = 0; i < 2; ++i) {
        bfr[i][0] = *(const bf16x8*)(bp[i]);
        bfr[i][1] = *(const bf16x8*)(bp[i] + 8);
    }

    f32x4 zero = {0.f, 0.f, 0.f, 0.f};
    f32x4 o[2][4];
    #pragma unroll
    for (int i = 0; i < 2; ++i)
        #pragma unroll
        for (int j = 0; j < 4; ++j) o[i][j] = zero;
    float m_i[2][4], l_i[2][4];
    #pragma unroll
    for (int i = 0; i < 2; ++i)
        #pragma unroll
        for (int r = 0; r < 4; ++r) { m_i[i][r] = -1e30f; l_i[i][r] = 0.f; }

    char* psb = (char*)&Ps[w][0];

    for (int kt16 = 0; kt16 < 16; ++kt16) {
        const int cur = kt16 & 1;
        __syncthreads();    // publishes tile kt16 (drains in-flight prefetch)

        // prefetch tile kt16+1 into the other buffer (uniform branch)
        if (kt16 < 15) {
            const size_t kn = (size_t)(kt16 + 1) * 64;
            unsigned short* kd = kst + (cur ^ 1) * 4096;
            unsigned short* vd = vst + (cur ^ 1) * 4096;
            GLDS(kg + kn * 1024, kd);
            GLDS(kg + (kn + 32) * 1024, kd + 32 * 64);
            GLDS(vg + kn, vd);
            GLDS(vg + kn + (size_t)32 * 1024, vd + 32 * 64);
        }

        const unsigned short* Kc = &Ks[0][0] + cur * 4096;
        const unsigned short* Vc = &Vs[0][0] + cur * 4096;

        // S = bias + Q K^T (bias as accumulator init), both row-tiles
        f32x4 s[2][4];
        #pragma unroll
        for (int i = 0; i < 2; ++i)
            #pragma unroll
            for (int j = 0; j < 2; ++j)
                #pragma unroll
                for (int r = 0; r < 4; ++r) {
                    s[i][j][r]     = bf2f((unsigned short)bfr[i][0][j * 4 + r]);
                    s[i][2 + j][r] = bf2f((unsigned short)bfr[i][1][j * 4 + r]);
                }

        __builtin_amdgcn_s_setprio(1);
        #pragma unroll
        for (int j = 0; j < 4; ++j) {
            #pragma unroll
            for (int c = 0; c < 2; ++c) {
                bf16x8 kf = *(const bf16x8*)(Kc + (j * 16 + lane16) * 64
                                             + (((c * 4 + quad) ^ (lane16 & 7)) * 8));
                #pragma unroll
                for (int i = 0; i < 2; ++i)
                    s[i][j] = MFMA(qf[i][c], kf, s[i][j]);
            }
        }
        __builtin_amdgcn_s_setprio(0);

        // prefetch bias fragments for next tile (bfr consumed above)
        if (kt16 < 15) {
            #pragma unroll
            for (int i = 0; i < 2; ++i) {
                bfr[i][0] = *(const bf16x8*)(bp[i] + (size_t)(kt16 + 1) * 1024);
                bfr[i][1] = *(const bf16x8*)(bp[i] + (size_t)(kt16 + 1) * 1024 + 8);
            }
        }

        // per row-tile: softmax, then P transpose through the SINGLE per-wave
        // Ps buffer (write i -> read pf[i] -> reuse buffer for i+1; per-wave
        // DS ops are in-order so WAR on the buffer is safe)
        bf16x8 pf[2][2];
        float alpha_r[2][4];
        #pragma unroll
        for (int i = 0; i < 2; ++i) {
            float p_[4][4];
            #pragma unroll
            for (int r = 0; r < 4; ++r) {
                float mx = fmaxf(fmaxf(s[i][0][r], s[i][1][r]), fmaxf(s[i][2][r], s[i][3][r]));
                #pragma unroll
                for (int d = 1; d < 16; d <<= 1) mx = fmaxf(mx, __shfl_xor(mx, d, 64));
                float mnew = fmaxf(m_i[i][r], mx);
                float alpha = __expf(m_i[i][r] - mnew);
                m_i[i][r] = mnew;
                alpha_r[i][r] = alpha;
                #pragma unroll
                for (int j = 0; j < 4; ++j) p_[j][r] = __expf(s[i][j][r] - mnew);
                #pragma unroll
                for (int jd = 0; jd < 4; ++jd) o[i][jd][r] *= alpha;
            }

            #pragma unroll
            for (int j = 0; j < 4; ++j)
                #pragma unroll
                for (int r = 0; r < 4; ++r) {
                    int row = quad * 4 + r;
                    int cb = (j * 16 + lane16) * 2;
                    *(unsigned short*)(psb + row * 128 + (cb ^ ((row & 7) << 4))) = f2bf(p_[j][r]);
                }
            asm volatile("" ::: "memory");
            #pragma unroll
            for (int c = 0; c < 2; ++c) {
                int cb = c * 64 + quad * 16;
                pf[i][c] = *(const bf16x8*)(psb + lane16 * 128 + (cb ^ ((lane16 & 7) << 4)));
            }
            asm volatile("" ::: "memory");
        }

        // O += P V ; V fragments shared across row-tiles
        f32x4 lacc[2] = {zero, zero};
        __builtin_amdgcn_s_setprio(1);
        #pragma unroll
        for (int jd = 0; jd < 4; ++jd)
            #pragma unroll
            for (int c = 0; c < 2; ++c) {
                bf16x8 vf = *(const bf16x8*)(Vc + (jd * 16 + lane16) * 64
                                             + (((c * 4 + quad) ^ (lane16 & 7)) * 8));
                #pragma unroll
                for (int i = 0; i < 2; ++i)
                    o[i][jd] = MFMA(pf[i][c], vf, o[i][jd]);
            }
        #pragma unroll
        for (int i = 0; i < 2; ++i)
            #pragma unroll
            for (int c = 0; c < 2; ++c)
                lacc[i] = MFMA(pf[i][c], ones, lacc[i]);
        __builtin_amdgcn_s_setprio(0);

        #pragma unroll
        for (int i = 0; i < 2; ++i)
            #pragma unroll
            for (int r = 0; r < 4; ++r)
                l_i[i][r] = l_i[i][r] * alpha_r[i][r] + lacc[i][r];
        // no trailing barrier: next top-barrier protects buffer reuse
    }

    #pragma unroll
    for (int i = 0; i < 2; ++i) {
        float inv[4];
        #pragma unroll
        for (int r = 0; r < 4; ++r) inv[r] = 1.0f / l_i[i][r];
        #pragma unroll
        for (int jd = 0; jd < 4; ++jd)
            #pragma unroll
            for (int r = 0; r < 4; ++r)
                Xp[(size_t)(b * 1024 + qrow0 + i * 16 + quad * 4 + r) * 1024
                   + h * 64 + jd * 16 + lane16] = f2bf(o[i][jd][r] * inv[r]);
    }
}

// ---------------------------------------------------------------------------
// O-projection GEMM, 128x64 tile, 1D grid 512 with id%8 = m%8 so the 16
// n-blocks sharing an A-panel co-locate on one XCD (A traffic 64->8 MB).
// C[4096,1024] f32 = X(bf16) @ W^T + b. 4 waves as 2x2 of 64x32.
// ---------------------------------------------------------------------------
__global__ __launch_bounds__(256, 2) void gemm_o64(
    const unsigned short* __restrict__ X, const unsigned short* __restrict__ W,
    const float* __restrict__ bvec, float* __restrict__ Y)
{
    __shared__ unsigned short As[128 * 32];
    __shared__ unsigned short Bs[64 * 32];

    const int t = threadIdx.x;
    const int w = t >> 6, l = t & 63;
    const int lane16 = l & 15, quad = l >> 4;
    const int id = blockIdx.x;
    const int m0 = (id & 31) * 128;      // id%8 = m%8 -> XCD by m
    const int n0 = (id >> 5) * 64;
    const int wr = w >> 1, wc = w & 1;

    const int srow = w * 16 + (l >> 2);                 // 0..63
    const unsigned short* agp = X + (size_t)(m0 + srow) * 1024 + (l & 3) * 8;
    const unsigned short* bgp = W + (size_t)(n0 + srow) * 1024 + (l & 3) * 8;
    unsigned short* alp = As + w * 512 + l * 8;
    unsigned short* blp = Bs + w * 512 + l * 8;

    f32x4 zero = {0.f, 0.f, 0.f, 0.f};
    f32x4 acc[4][2];
    #pragma unroll
    for (int i = 0; i < 4; ++i)
        #pragma unroll
        for (int j = 0; j < 2; ++j) acc[i][j] = zero;

    for (int kt = 0; kt < 1024; kt += 32) {
        GLDS(agp + kt, alp);
        GLDS(agp + kt + 64 * 1024, alp + 2048);
        GLDS(bgp + kt, blp);
        __syncthreads();

        bf16x8 af[4], bfv[2];
        #pragma unroll
        for (int i = 0; i < 4; ++i)
            af[i] = *(const bf16x8*)(As + (wr * 64 + i * 16 + lane16) * 32 + quad * 8);
        #pragma unroll
        for (int j = 0; j < 2; ++j)
            bfv[j] = *(const bf16x8*)(Bs + (wc * 32 + j * 16 + lane16) * 32 + quad * 8);

        #pragma unroll
        for (int i = 0; i < 4; ++i)
            #pragma unroll
            for (int j = 0; j < 2; ++j)
                acc[i][j] = MFMA(af[i], bfv[j], acc[i][j]);
        __syncthreads();
    }

    float bvl[2];
    #pragma unroll
    for (int j = 0; j < 2; ++j) bvl[j] = bvec[n0 + wc * 32 + j * 16 + lane16];

    #pragma unroll
    for (int i = 0; i < 4; ++i)
        #pragma unroll
        for (int j = 0; j < 2; ++j) {
            int n = n0 + wc * 32 + j * 16 + lane16;
            #pragma unroll
            for (int r = 0; r < 4; ++r) {
                size_t m = m0 + wr * 64 + i * 16 + quad * 4 + r;
                Y[m * 1024 + n] = acc[i][j][r] + bvl[j];
            }
        }
}

// ---------------------------------------------------------------------------
extern "C" void kernel_launch(void* const* d_in, const int* in_sizes, int n_in,
                              void* d_out, int out_size, void* d_ws, size_t ws_size,
                              hipStream_t stream)
{
    const float* query = (const float*)d_in[0];
    const float* key   = (const float*)d_in[1];
    const float* value = (const float*)d_in[2];
    const float* abias = (const float*)d_in[3];
    const int*   mask  = (const int*)d_in[4];
    const float* Wq = (const float*)d_in[5];
    const float* bq = (const float*)d_in[6];
    const float* Wk = (const float*)d_in[7];
    const float* bk = (const float*)d_in[8];
    const float* Wv = (const float*)d_in[9];
    const float* bv = (const float*)d_in[10];
    const float* Wo = (const float*)d_in[11];
    const float* bo = (const float*)d_in[12];
    float* out = (float*)d_out;

    const size_t T = (size_t)B_ * S_ * D_;           // 4 Mi
    const size_t WSZ = (size_t)D_ * D_;              // 1 Mi
    const size_t BPSZ = (size_t)B_ * H_ * S_ * S_;   // 64 Mi
    unsigned short* p = (unsigned short*)d_ws;
    unsigned short* biasP = p;  p += BPSZ;
    unsigned short* qb  = p;  p += T;
    unsigned short* kb  = p;  p += T;
    unsigned short* vb  = p;  p += T;
    unsigned short* wqb = p;  p += WSZ;
    unsigned short* wkb = p;  p += WSZ;
    unsigned short* wvb = p;  p += WSZ;
    unsigned short* wob = p;  p += WSZ;
    unsigned short* Qpj = p;  p += T;
    unsigned short* Kpj = p;  p += T;
    unsigned short* VpT = p;  p += T;
    unsigned short* Xpj = p;  p += T;

    cvt_all<<<dim3(16384), 256, 0, stream>>>(
        query, key, value, Wq, Wk, Wv, Wo,
        qb, kb, vb, wqb, wkb, wvb, wob);

    prep_bias<<<dim3(4096), 256, 0, stream>>>(abias, mask, biasP);

    gemm128<<<dim3(768), 256, 0, stream>>>(
        qb, kb, vb, wqb, wkb, wvb, bq, bk, bv,
        Qpj, Kpj, VpT, mask);

    attn_mfma<<<dim3(512), 256, 0, stream>>>(Qpj, Kpj, VpT, biasP, Xpj);

    gemm_o64<<<dim3(512), 256, 0, stream>>>(Xpj, wob, bo, out);
}